// Round 4
// baseline (123.222 us; speedup 1.0000x reference)
//
#include <hip/hip_runtime.h>

// MonotoneActivation: per (b,g) group of ARITY=4 inputs, sort-4, barycentric
// interpolation over the 2^4 lattice, OUT_DIM=4 outputs.
//
// R3 design == R2 (LDS-staged 32KB half-table, 512-thread blocks, 32 waves/CU,
// non-temporal X/out streaming) with the nontemporal builtins applied to clang
// ext_vector_type(4) float (HIP_vector_type structs are rejected by the builtin).

#define GROUPS        256
#define CHUNK_G       128                  // groups per block
#define ROWS_PER_BLK  32
#define BATCH         16384
#define NBLOCKS       (2 * (BATCH / ROWS_PER_BLK))   // 1024 = 4 blocks/CU
#define BLOCK_T       512

typedef float f4 __attribute__((ext_vector_type(4)));

__global__ __launch_bounds__(BLOCK_T, 8) void mono_act_kernel(
    const float* __restrict__ X,
    const float* __restrict__ params,   // [GROUPS, 16, 4] floats
    float* __restrict__ out)            // [BATCH, GROUPS*4]
{
    __shared__ f4 lut[16 * CHUNK_G];       // 32 KB: lut[e*CHUNK_G + g]

    const int t     = threadIdx.x;
    const int chunk = blockIdx.x & 1;        // which 128-group half
    const int slab  = blockIdx.x >> 1;       // which 32-row slab

    // ---- stage params chunk into LDS, transposed to [e][g] ----
    const f4* __restrict__ P = reinterpret_cast<const f4*>(params);
    #pragma unroll
    for (int i = 0; i < 4; ++i) {
        int idx = i * BLOCK_T + t;           // 0..2047 == e*128 + g
        int e   = idx >> 7;
        int g   = idx & (CHUNK_G - 1);
        lut[idx] = P[((size_t)(chunk * CHUNK_G + g) << 4) + e];
    }
    __syncthreads();

    // ---- compute: 512 threads cover 4 rows x 128 groups per iteration ----
    const int g    = t & (CHUNK_G - 1);
    const int rsub = t >> 7;                 // 0..3
    const int r0   = slab * ROWS_PER_BLK + rsub;

    // f4 index of (row r, this chunk, group g) in X/out
    const f4* __restrict__ X4 =
        reinterpret_cast<const f4*>(X) + (size_t)chunk * CHUNK_G + g;
    f4* __restrict__ O4 =
        reinterpret_cast<f4*>(out) + (size_t)chunk * CHUNK_G + g;

    #pragma unroll 4
    for (int k = 0; k < ROWS_PER_BLK / 4; ++k) {
        const size_t roff = (size_t)(r0 + 4 * k) * GROUPS;  // f4 units
        const f4 x = __builtin_nontemporal_load(&X4[roff]);

        float a0 = x.x, a1 = x.y, a2 = x.z, a3 = x.w;
        int i0 = 1, i1 = 2, i2 = 4, i3 = 8;   // 1 << original index

        // stable sorting network (strict >): (0,1)(2,3)(0,2)(1,3)(1,2)
#define CEX(a, b, ia, ib)                                   \
        do {                                                \
            if (a > b) {                                    \
                float _t = a; a = b; b = _t;                \
                int _u = ia; ia = ib; ib = _u;              \
            }                                               \
        } while (0)
        CEX(a0, a1, i0, i1);
        CEX(a2, a3, i2, i3);
        CEX(a0, a2, i0, i2);
        CEX(a1, a3, i1, i3);
        CEX(a1, a2, i1, i2);
#undef CEX

        const float c0 = a0;
        const float c1 = a1 - a0;
        const float c2 = a2 - a1;
        const float c3 = a3 - a2;

        // reversed-cumsum lattice indices; e0==15 -> corner==1.0 (projected)
        const int e3 = i3;
        const int e2 = e3 | i2;
        const int e1 = e2 | i1;

        const f4 p1 = lut[(e1 << 7) + g];
        const f4 p2 = lut[(e2 << 7) + g];
        const f4 p3 = lut[(e3 << 7) + g];

        f4 r;
        r.x = c0 + c1 * p1.x + c2 * p2.x + c3 * p3.x;
        r.y = c0 + c1 * p1.y + c2 * p2.y + c3 * p3.y;
        r.z = c0 + c1 * p1.z + c2 * p2.z + c3 * p3.z;
        r.w = c0 + c1 * p1.w + c2 * p2.w + c3 * p3.w;

        __builtin_nontemporal_store(r, &O4[roff]);
    }
}

extern "C" void kernel_launch(void* const* d_in, const int* in_sizes, int n_in,
                              void* d_out, int out_size, void* d_ws, size_t ws_size,
                              hipStream_t stream) {
    const float* X      = (const float*)d_in[0];
    const float* params = (const float*)d_in[1];
    float* out          = (float*)d_out;

    mono_act_kernel<<<NBLOCKS, BLOCK_T, 0, stream>>>(X, params, out);
}

// Round 5
// 117.061 us; speedup vs baseline: 1.0526x; 1.0526x over previous
//
#include <hip/hip_runtime.h>

// MonotoneActivation: per (b,g) group of ARITY=4 inputs, sort-4, barycentric
// interpolation over the 2^4 lattice, OUT_DIM=4 outputs.
//
// R5 design: cached (non-nt) streaming — X is L3-resident after harness
// restore and L3 absorbs out writebacks, so nt hints regressed (R4).
// Occupancy fix via smaller LDS: 16 KB chunk (64 groups) per 256-thread
// block -> 8 blocks/CU x 4 waves = 32 waves/CU (100%), vs R1's LDS-capped
// 5 blocks. Grid 2048. LDS layout [e][g]: lanes = consecutive g =
// consecutive 16B -> conflict-free ds_read_b128.

#define GROUPS        256
#define CHUNK_G       64                   // groups per block (16 KB LDS)
#define NCHUNK        (GROUPS / CHUNK_G)   // 4
#define ROWS_PER_BLK  32
#define BATCH         16384
#define NBLOCKS       (NCHUNK * (BATCH / ROWS_PER_BLK))   // 2048 = 8 blocks/CU
#define BLOCK_T       256

typedef float f4 __attribute__((ext_vector_type(4)));

__global__ __launch_bounds__(BLOCK_T, 8) void mono_act_kernel(
    const float* __restrict__ X,
    const float* __restrict__ params,   // [GROUPS, 16, 4] floats
    float* __restrict__ out)            // [BATCH, GROUPS*4]
{
    __shared__ f4 lut[16 * CHUNK_G];       // 16 KB: lut[e*CHUNK_G + g]

    const int t     = threadIdx.x;
    const int chunk = blockIdx.x & (NCHUNK - 1);   // which 64-group quarter
    const int slab  = blockIdx.x >> 2;             // which 32-row slab

    // ---- stage params chunk into LDS, transposed to [e][g] ----
    const f4* __restrict__ P = reinterpret_cast<const f4*>(params);
    #pragma unroll
    for (int i = 0; i < 4; ++i) {
        int idx = i * BLOCK_T + t;           // 0..1023 == e*64 + g
        int e   = idx >> 6;
        int g   = idx & (CHUNK_G - 1);
        lut[idx] = P[((size_t)(chunk * CHUNK_G + g) << 4) + e];
    }
    __syncthreads();

    // ---- compute: 256 threads cover 4 rows x 64 groups per iteration ----
    const int g    = t & (CHUNK_G - 1);
    const int rsub = t >> 6;                 // 0..3
    const int r0   = slab * ROWS_PER_BLK + rsub;

    // f4 index of (row r, this chunk, group g) in X/out
    const f4* __restrict__ X4 =
        reinterpret_cast<const f4*>(X) + (size_t)chunk * CHUNK_G + g;
    f4* __restrict__ O4 =
        reinterpret_cast<f4*>(out) + (size_t)chunk * CHUNK_G + g;

    #pragma unroll 4
    for (int k = 0; k < ROWS_PER_BLK / 4; ++k) {
        const size_t roff = (size_t)(r0 + 4 * k) * GROUPS;  // f4 units
        const f4 x = X4[roff];

        float a0 = x.x, a1 = x.y, a2 = x.z, a3 = x.w;
        int i0 = 1, i1 = 2, i2 = 4, i3 = 8;   // 1 << original index

        // stable sorting network (strict >): (0,1)(2,3)(0,2)(1,3)(1,2)
#define CEX(a, b, ia, ib)                                   \
        do {                                                \
            if (a > b) {                                    \
                float _t = a; a = b; b = _t;                \
                int _u = ia; ia = ib; ib = _u;              \
            }                                               \
        } while (0)
        CEX(a0, a1, i0, i1);
        CEX(a2, a3, i2, i3);
        CEX(a0, a2, i0, i2);
        CEX(a1, a3, i1, i3);
        CEX(a1, a2, i1, i2);
#undef CEX

        const float c0 = a0;
        const float c1 = a1 - a0;
        const float c2 = a2 - a1;
        const float c3 = a3 - a2;

        // reversed-cumsum lattice indices; e0==15 -> corner==1.0 (projected)
        const int e3 = i3;
        const int e2 = e3 | i2;
        const int e1 = e2 | i1;

        const f4 p1 = lut[(e1 << 6) + g];
        const f4 p2 = lut[(e2 << 6) + g];
        const f4 p3 = lut[(e3 << 6) + g];

        f4 r;
        r.x = c0 + c1 * p1.x + c2 * p2.x + c3 * p3.x;
        r.y = c0 + c1 * p1.y + c2 * p2.y + c3 * p3.y;
        r.z = c0 + c1 * p1.z + c2 * p2.z + c3 * p3.z;
        r.w = c0 + c1 * p1.w + c2 * p2.w + c3 * p3.w;

        O4[roff] = r;
    }
}

extern "C" void kernel_launch(void* const* d_in, const int* in_sizes, int n_in,
                              void* d_out, int out_size, void* d_ws, size_t ws_size,
                              hipStream_t stream) {
    const float* X      = (const float*)d_in[0];
    const float* params = (const float*)d_in[1];
    float* out          = (float*)d_out;

    mono_act_kernel<<<NBLOCKS, BLOCK_T, 0, stream>>>(X, params, out);
}